// Round 12
// baseline (128.696 us; speedup 1.0000x reference)
//
#include <hip/hip_runtime.h>
#include <math.h>

// FourierLayer: B=8, C=64, H=256, W=256, M1=M2=16.
// Pipeline:
//   AB (fused MFMA, h-split): per (bc, h-half): phase1 U[32][128h] = TA . x^T ;
//       phase2 X_part[64][16ky] = TB[.,h-slice] . U2 ; partials summed in C.
//   Wprep: Wt[kxi][ky][i][o] = (kxi<16 ? w1 : w2)[i][o][kxi&15][ky]
//   C: Y2[b][o][ky][kxi] (i-split partials A/B) = sum_i (XA+XB) * Wt  (complex, f32)
//   D (MFMA): Z[b][o][h][ky] = sum_kxi sc(ky)*(YrA+YrB, YiA+YiB).(trig), h-quartered,
//       stored as bf16 ushort arrays Zrb/Zib (pack moved here from E; identical values)
//   E (MFMA): out[64o][128w-half] = [cw | Zr | Zi] (64x96 bf16) @ [x ; cos ; -sin] + bias
//       k 0..63 conv, k 64..79 Zr(ky)*cos, k 80..95 Zi(ky)*(-sin)

#define TWOPI_256 0.024543692606170259f   // 2*pi/256
#define INV256    0.00390625f

// ---------------- workspace layout (floats) ----------------
#define NX   262144             // X/Y size: 8*64*512
#define NWT  2097152            // 32*16*64*64
#define NZH  1048576            // bf16 Z plane: 2097152 ushort = NZH float slots
#define O_TA   0                // 8192 ushort  (32x256 bf16)
#define O_TB   4096             // 32768 ushort (64x512 bf16)
#define O_XRA  20480
#define O_XIA  (O_XRA + NX)
#define O_XRB  (O_XIA + NX)
#define O_XIB  (O_XRB + NX)
#define O_WTR  (O_XIB + NX)
#define O_WTI  (O_WTR + NWT)
#define O_YRA  (O_WTI + NWT)
#define O_YIA  (O_YRA + NX)
#define O_YRB  (O_YIA + NX)
#define O_YIB  (O_YRB + NX)
#define O_ZRB  (O_YIB + NX)     // ushort[2097152]: Zr bf16 [b][o][h][16ky]
#define O_ZIB  (O_ZRB + NZH)    // ushort[2097152]: Zi bf16
#define O_TT   (O_ZIB + NZH)    // E trig table ttab2: 8192 ushort
#define O_TD   (O_TT + 4096)    // D trig table: 32768 ushort ([2 ri][256 h][64 k])
// end = O_TD + 16384 ~= 8.43M floats ~= 33.7 MiB

using s16x8 = __attribute__((ext_vector_type(8))) short;   // 8 bf16 (4 VGPRs)
using f32x4 = __attribute__((ext_vector_type(4))) float;   // MFMA acc
using u32x4 = __attribute__((ext_vector_type(4))) unsigned;

__device__ __forceinline__ unsigned short f2bf(float f) {  // RNE f32->bf16 (table gen only)
    union { float f; unsigned u; } a; a.f = f;
    unsigned r = (a.u + 0x7fffu + ((a.u >> 16) & 1u)) >> 16;
    return (unsigned short)r;
}

// pure-C packed convert (round-half-up): lo16 = bf16(a), hi16 = bf16(b)
__device__ __forceinline__ unsigned bfpack(float a, float b) {
    union { float f; unsigned u; } x, y; x.f = a; y.f = b;
    return ((x.u + 0x8000u) >> 16) | ((y.u + 0x8000u) & 0xffff0000u);
}

// ---------------- table gen: TA + TB + TD + TT(E) ----------------
__global__ __launch_bounds__(256) void ktabs(unsigned short* __restrict__ tA,
                                             unsigned short* __restrict__ tB,
                                             unsigned short* __restrict__ tD,
                                             unsigned short* __restrict__ tT) {
    int idx = blockIdx.x * 256 + threadIdx.x;     // 81920 total
    if (idx < 8192) {
        // TA[col][w]: col<16 -> cos(2pi col w/256)/256 ; col>=16 -> -sin(...)/256
        int col = idx >> 8, w = idx & 255;
        int ky = col & 15;
        int mm = (ky * w) & 255;
        float s, c; sincosf((float)mm * TWOPI_256, &s, &c);
        tA[idx] = f2bf(col < 16 ? c * INV256 : -s * INV256);
    } else if (idx < 40960) {
        // TB[kx2][2h+p]: kx2<32 (Re): p0=cos, p1=sin ; kx2>=32 (Im): p0=-sin, p1=cos
        int j = idx - 8192;
        int kx2 = j >> 9, k = j & 511, h = k >> 1, p = k & 1;
        int kxi = kx2 & 31;
        int kx = (kxi < 16) ? kxi : (224 + kxi);
        int mm = (kx * h) & 255;
        float s, c; sincosf((float)mm * TWOPI_256, &s, &c);
        float v;
        if (kx2 < 32) v = p ? s : c;
        else          v = p ? c : -s;
        tB[j] = f2bf(v);
    } else if (idx < 73728) {
        // TD[ri][h][k=2kxi+p], e^{+2pi i kx h/256}:
        //   ri=0 (Zr): p0 = cos, p1 = -sin ; ri=1 (Zi): p0 = sin, p1 = cos
        int j = idx - 40960;
        int ri = j >> 14, rem = j & 16383;
        int h = rem >> 6, k = rem & 63, kxi = k >> 1, p = k & 1;
        int kx = (kxi < 16) ? kxi : (224 + kxi);
        int mm = (kx * h) & 255;
        float s, c; sincosf((float)mm * TWOPI_256, &s, &c);
        float v;
        if (ri == 0) v = p ? -s : c;
        else         v = p ? c : s;
        tD[j] = f2bf(v);
    } else {
        // TT2[w][kk] for E: kk<16 -> cos(2pi kk w/256) ; kk>=16 -> -sin(2pi (kk-16) w/256)
        int j = idx - 73728;
        int w = j >> 5, kk = j & 31, ky = kk & 15;
        int mm = (ky * w) & 255;
        float s, c; sincosf((float)mm * TWOPI_256, &s, &c);
        tT[j] = f2bf(kk < 16 ? c : -s);
    }
}

// ---------------- Kernel AB (fused MFMA, h-split): x -> X partials ----------
// grid 1024 = bc(512) x h-half(2). block 256 (4 waves). Reg-double-buffered staging.
__global__ __launch_bounds__(256, 4) void kab_fwd(const float* __restrict__ x,
                                                  const unsigned short* __restrict__ tA,
                                                  const unsigned short* __restrict__ tB,
                                                  float* __restrict__ XrA,
                                                  float* __restrict__ XiA,
                                                  float* __restrict__ XrB,
                                                  float* __restrict__ XiB) {
    __shared__ __align__(16) unsigned short xt[8192];   // 16 KB [128h][64w] bf16 swz
    __shared__ __align__(16) unsigned int   ub[2048];   // 8 KB U2 [16ky][256k] swz
    const int tid  = threadIdx.x;
    const int bc   = blockIdx.x >> 1;
    const int hhf  = blockIdx.x & 1;
    const int hbase = hhf << 7;
    const int m    = tid & 15;
    const int g    = (tid >> 4) & 3;
    const int wave = tid >> 6;

    const float* xp = x + (size_t)bc * 65536 + (size_t)hbase * 256;
    const int hh = tid >> 4;        // 0..15: h offset within 16-row group
    const int w4 = tid & 15;        // float4 index along w

    f32x4 acc[2][2];
#pragma unroll
    for (int a = 0; a < 2; ++a)
#pragma unroll
        for (int fn = 0; fn < 2; ++fn)
#pragma unroll
            for (int r = 0; r < 4; ++r) acc[a][fn][r] = 0.f;

    float4 stg[2][8];
#pragma unroll
    for (int it = 0; it < 8; ++it)
        stg[0][it] = *reinterpret_cast<const float4*>(xp + (it * 16 + hh) * 256 + w4 * 4);

#pragma unroll
    for (int ch = 0; ch < 4; ++ch) {
        const int cur = ch & 1;
        if (ch < 3) {
#pragma unroll
            for (int it = 0; it < 8; ++it)
                stg[cur ^ 1][it] = *reinterpret_cast<const float4*>(
                    xp + (it * 16 + hh) * 256 + (ch + 1) * 64 + w4 * 4);
        }
#pragma unroll
        for (int it = 0; it < 8; ++it) {
            int h = it * 16 + hh;                    // local h 0..127
            float4 v = stg[cur][it];
            unsigned lo = bfpack(v.x, v.y);
            unsigned hi = bfpack(v.z, v.w);
            int wl  = w4 * 4;
            int blk = (wl >> 3) ^ (h & 7);
            char* p = reinterpret_cast<char*>(xt) + (h << 7) + (blk << 4) + ((wl & 7) << 1);
            *reinterpret_cast<uint2*>(p) = make_uint2(lo, hi);
        }
        __syncthreads();
#pragma unroll
        for (int ks = 0; ks < 2; ++ks) {
            s16x8 a0 = *reinterpret_cast<const s16x8*>(tA + m * 256        + ch * 64 + ks * 32 + 8 * g);
            s16x8 a1 = *reinterpret_cast<const s16x8*>(tA + (16 + m) * 256 + ch * 64 + ks * 32 + 8 * g);
#pragma unroll
            for (int fn = 0; fn < 2; ++fn) {
                int h   = wave * 32 + fn * 16 + m;   // local h
                int blk = (4 * ks + g) ^ (h & 7);
                s16x8 bf = *reinterpret_cast<const s16x8*>(
                    reinterpret_cast<const char*>(xt) + (h << 7) + (blk << 4));
                acc[0][fn] = __builtin_amdgcn_mfma_f32_16x16x32_bf16(a0, bf, acc[0][fn], 0, 0, 0);
                acc[1][fn] = __builtin_amdgcn_mfma_f32_16x16x32_bf16(a1, bf, acc[1][fn], 0, 0, 0);
            }
        }
        __syncthreads();
    }

    // ---- redistribute U -> ub: word h(local) of row ky holds (Ur,Ui) bf16 pair ----
#pragma unroll
    for (int fn = 0; fn < 2; ++fn) {
        int h = wave * 32 + fn * 16 + m;
#pragma unroll
        for (int r = 0; r < 4; ++r) {
            int ky = 4 * g + r;
            unsigned pk = bfpack(acc[0][fn][r], acc[1][fn][r]);
            int blk = (h >> 2) ^ (ky & 7);
            ub[ky * 128 + blk * 4 + (h & 3)] = pk;
        }
    }
    __syncthreads();

    // ---- phase-2 MFMA: X_part[64][16] = TB[64][k-slice] . U2[256][16] ----
    f32x4 acc2;
#pragma unroll
    for (int r = 0; r < 4; ++r) acc2[r] = 0.f;
#pragma unroll
    for (int ks = 0; ks < 8; ++ks) {
        s16x8 a2 = *reinterpret_cast<const s16x8*>(tB + (wave * 16 + m) * 512 + hbase * 2 + ks * 32 + 8 * g);
        int blk = (4 * ks + g) ^ (m & 7);
        s16x8 b2 = *reinterpret_cast<const s16x8*>(
            reinterpret_cast<const char*>(ub) + m * 512 + (blk << 4));
        acc2 = __builtin_amdgcn_mfma_f32_16x16x32_bf16(a2, b2, acc2, 0, 0, 0);
    }
    float* Xr = hhf ? XrB : XrA;
    float* Xi = hhf ? XiB : XiA;
#pragma unroll
    for (int r = 0; r < 4; ++r) {
        int kx2 = wave * 16 + 4 * g + r;
        if (kx2 < 32) Xr[(size_t)bc * 512 + kx2 * 16 + m]        = acc2[r];
        else          Xi[(size_t)bc * 512 + (kx2 - 32) * 16 + m] = acc2[r];
    }
}

// ---------------- Kernel Wprep: weight transpose --------------
__global__ __launch_bounds__(256) void kw_prep(const float* __restrict__ w1r,
                                               const float* __restrict__ w1i,
                                               const float* __restrict__ w2r,
                                               const float* __restrict__ w2i,
                                               float* __restrict__ Wtr,
                                               float* __restrict__ Wti) {
    __shared__ float lds[128][65];
    const int tid = threadIdx.x;
    const int a = blockIdx.x >> 6;
    const int i = blockIdx.x & 63;
    const float* src = (a == 0) ? w1r : (a == 1) ? w1i : (a == 2) ? w2r : w2i;
    float* dst = (a & 1) ? Wti : Wtr;
    const int kxoff = (a >> 1) << 4;
    const float* sp = src + (size_t)i * 16384;

    for (int p = 0; p < 2; ++p) {
        if (p) __syncthreads();
#pragma unroll
        for (int it = 0; it < 8; ++it) {
            int f4 = it * 256 + tid;
            int o = f4 >> 5, j4 = f4 & 31;
            float4 v = *reinterpret_cast<const float4*>(sp + o * 256 + p * 128 + j4 * 4);
            lds[j4 * 4 + 0][o] = v.x; lds[j4 * 4 + 1][o] = v.y;
            lds[j4 * 4 + 2][o] = v.z; lds[j4 * 4 + 3][o] = v.w;
        }
        __syncthreads();
        const int o = tid & 63, mq = tid >> 6;
#pragma unroll
        for (int r = 0; r < 32; ++r) {
            int lm = r * 4 + mq;
            int mky = p * 128 + lm;
            int mm = mky >> 4, ky = mky & 15;
            dst[((((size_t)(kxoff + mm)) * 16 + ky) * 64 + i) * 64 + o] = lds[lm][o];
        }
    }
}

// ---------------- Kernel C: channel mixing (i-split) -> Y partial A/B --------
// grid 1024 = mode(512) x ih(2). Each block sums 32 i's; X = XA + XB partials.
__global__ __launch_bounds__(256) void kc_mix(const float* __restrict__ XrA,
                                              const float* __restrict__ XiA,
                                              const float* __restrict__ XrB,
                                              const float* __restrict__ XiB,
                                              const float* __restrict__ Wtr,
                                              const float* __restrict__ Wti,
                                              float* __restrict__ YrA,
                                              float* __restrict__ YiA,
                                              float* __restrict__ YrB,
                                              float* __restrict__ YiB) {
    __shared__ float xsr[256], xsi[256];
    const int tid  = threadIdx.x;
    const int mode = blockIdx.x >> 1;
    const int ih   = blockIdx.x & 1;
    {
        int b = tid >> 5, il = tid & 31;
        size_t ofs = (size_t)(b * 64 + ih * 32 + il) * 512 + mode;
        xsr[tid] = XrA[ofs] + XrB[ofs];
        xsi[tid] = XiA[ofs] + XiB[ofs];
    }
    __syncthreads();
    const int o = tid & 63, bg = tid >> 6;
    float yr0 = 0.f, yi0 = 0.f, yr1 = 0.f, yi1 = 0.f;
    const float* wrp = Wtr + (size_t)mode * 4096 + ih * 2048;
    const float* wip = Wti + (size_t)mode * 4096 + ih * 2048;
#pragma unroll 8
    for (int i = 0; i < 32; ++i) {
        float wr = wrp[i * 64 + o], wi = wip[i * 64 + o];
        float xr = xsr[bg * 32 + i],        xi = xsi[bg * 32 + i];
        yr0 += xr * wr - xi * wi;  yi0 += xr * wi + xi * wr;
        float xr2 = xsr[(bg + 4) * 32 + i], xi2 = xsi[(bg + 4) * 32 + i];
        yr1 += xr2 * wr - xi2 * wi;  yi1 += xr2 * wi + xi2 * wr;
    }
    float* Yr = ih ? YrB : YrA;
    float* Yi = ih ? YiB : YiA;
    const int kxi = mode >> 4, kym = mode & 15;
    const size_t e0 = ((size_t)bg * 64 + o) * 512 + kym * 32 + kxi;
    const size_t e1 = ((size_t)(bg + 4) * 64 + o) * 512 + kym * 32 + kxi;
    Yr[e0] = yr0;  Yi[e0] = yi0;
    Yr[e1] = yr1;  Yi[e1] = yi1;
}

// ---------------- Kernel D (MFMA): Y(A+B) -> Z bf16 [b][o][h][ky] ----------
// grid 1024 = b(8) x og(16) x ri(2) x hs(4). block 256 (4 waves, wave = 16-h frag).
__global__ __launch_bounds__(256) void kd_mfma(const float* __restrict__ YrA,
                                               const float* __restrict__ YiA,
                                               const float* __restrict__ YrB,
                                               const float* __restrict__ YiB,
                                               const unsigned short* __restrict__ tD,
                                               unsigned short* __restrict__ Zrb,
                                               unsigned short* __restrict__ Zib) {
    __shared__ __align__(16) unsigned short at[4096];   // 8 KB: A[64 rows][64 k] swz
    __shared__ __align__(16) float zt[64][68];          // 17.4 KB: [h_local][m] + pad
    const int tid = threadIdx.x;
    const int bid = blockIdx.x;
    const int b  = bid >> 7;
    const int og = (bid >> 3) & 15;
    const int ri = (bid >> 2) & 1;
    const int hs = bid & 3;

    // ---- stage A: row = ol*16+ky, word j=kxi holds (Yr*sc, Yi*sc) bf16 ----
    {
        const int row = tid >> 2, q = tid & 3;
        const int ol = row >> 4, ky = row & 15;
        const float sc = (ky == 0) ? INV256 : 2.f * INV256;
        const size_t yb = ((size_t)(b * 64 + og * 4 + ol)) * 512 + ky * 32 + q * 8;
        f32x4 r0 = *reinterpret_cast<const f32x4*>(YrA + yb)     + *reinterpret_cast<const f32x4*>(YrB + yb);
        f32x4 r1 = *reinterpret_cast<const f32x4*>(YrA + yb + 4) + *reinterpret_cast<const f32x4*>(YrB + yb + 4);
        f32x4 i0 = *reinterpret_cast<const f32x4*>(YiA + yb)     + *reinterpret_cast<const f32x4*>(YiB + yb);
        f32x4 i1 = *reinterpret_cast<const f32x4*>(YiA + yb + 4) + *reinterpret_cast<const f32x4*>(YiB + yb + 4);
        unsigned wbuf[8];
#pragma unroll
        for (int t = 0; t < 4; ++t) {
            wbuf[t]     = bfpack(r0[t] * sc, i0[t] * sc);
            wbuf[4 + t] = bfpack(r1[t] * sc, i1[t] * sc);
        }
        char* base = reinterpret_cast<char*>(at) + row * 128;
        *reinterpret_cast<uint4*>(base + (((2 * q)     ^ (row & 7)) << 4)) = *reinterpret_cast<uint4*>(&wbuf[0]);
        *reinterpret_cast<uint4*>(base + (((2 * q + 1) ^ (row & 7)) << 4)) = *reinterpret_cast<uint4*>(&wbuf[4]);
    }
    __syncthreads();

    const int m = tid & 15, g = (tid >> 4) & 3, wid = tid >> 6;
    const unsigned short* td = tD + ri * 16384;
    const int hg = hs * 64 + wid * 16 + m;

    f32x4 acc[4];
#pragma unroll
    for (int mf = 0; mf < 4; ++mf)
#pragma unroll
        for (int r = 0; r < 4; ++r) acc[mf][r] = 0.f;

#pragma unroll
    for (int ks = 0; ks < 2; ++ks) {
        s16x8 bf = *reinterpret_cast<const s16x8*>(td + hg * 64 + ks * 32 + 8 * g);
#pragma unroll
        for (int mf = 0; mf < 4; ++mf) {
            s16x8 af = *reinterpret_cast<const s16x8*>(
                reinterpret_cast<const char*>(at) + (mf * 16 + m) * 128
                + (((4 * ks + g) ^ (m & 7)) << 4));
            acc[mf] = __builtin_amdgcn_mfma_f32_16x16x32_bf16(af, bf, acc[mf], 0, 0, 0);
        }
    }

#pragma unroll
    for (int mf = 0; mf < 4; ++mf)
#pragma unroll
        for (int r = 0; r < 4; ++r)
            zt[wid * 16 + m][mf * 16 + 4 * g + r] = acc[mf][r];
    __syncthreads();

    // ---- coalesced bf16 store: lane packs 4 ky -> uint2 (8B); 512B per instr ----
    unsigned short* Zd = ri ? Zib : Zrb;
    const int ol = tid >> 6, hloc = (tid >> 2) & 15, kg = tid & 3;
#pragma unroll
    for (int hq = 0; hq < 4; ++hq) {
        f32x4 v = *reinterpret_cast<const f32x4*>(&zt[hq * 16 + hloc][ol * 16 + 4 * kg]);
        unsigned lo = bfpack(v[0], v[1]);
        unsigned hi = bfpack(v[2], v[3]);
        size_t off = (((size_t)(b * 64 + og * 4 + ol)) * 256 + hs * 64 + hq * 16 + hloc) * 16 + 4 * kg;
        *reinterpret_cast<uint2*>(Zd + off) = make_uint2(lo, hi);
    }
}

// ---------------- Kernel E (MFMA): out = [cw|Zr|Zi] @ [x;cos;-sin] + bias ----
// grid 4096 = (b, h, w-half). block 256 (4 waves; wave = 16-o group x 128 w).
__global__ __launch_bounds__(256) void ke_mfma(const float* __restrict__ x,
                                               const unsigned short* __restrict__ Zrb,
                                               const unsigned short* __restrict__ Zib,
                                               const float* __restrict__ cw,
                                               const float* __restrict__ bias,
                                               const unsigned short* __restrict__ ttab,
                                               float* __restrict__ out) {
    __shared__ unsigned int bsx[4096];   // 16 KB: [128 w][32 words], swizzled
    const int tid = threadIdx.x;
    const int b  = blockIdx.x >> 9;
    const int h  = (blockIdx.x >> 1) & 255;
    const int wh = blockIdx.x & 1;
    const int wbase = wh * 128;

    const size_t xbase = ((size_t)b * 64) * 65536 + (size_t)h * 256 + wbase;
    const int wl4 = (tid & 31) * 4;
    const int ipg = tid >> 5;
    float4 va[4], vb[4];
#pragma unroll
    for (int it = 0; it < 4; ++it) {
        int ip = it * 8 + ipg;
        va[it] = *reinterpret_cast<const float4*>(x + xbase + (size_t)(2 * ip) * 65536 + wl4);
        vb[it] = *reinterpret_cast<const float4*>(x + xbase + (size_t)(2 * ip + 1) * 65536 + wl4);
    }

    const int m = tid & 15;
    const int g = (tid >> 4) & 3;
    const int wave = tid >> 6;
    const int o = wave * 16 + m;

    s16x8 a0, a1, az;
    {
        f32x4 p  = *reinterpret_cast<const f32x4*>(cw + o * 64 + 8 * g);
        f32x4 q  = *reinterpret_cast<const f32x4*>(cw + o * 64 + 8 * g + 4);
        f32x4 p2 = *reinterpret_cast<const f32x4*>(cw + o * 64 + 32 + 8 * g);
        f32x4 q2 = *reinterpret_cast<const f32x4*>(cw + o * 64 + 32 + 8 * g + 4);
        u32x4 t0 = {bfpack(p[0], p[1]),  bfpack(p[2], p[3]),
                    bfpack(q[0], q[1]),  bfpack(q[2], q[3])};
        u32x4 t1 = {bfpack(p2[0], p2[1]), bfpack(p2[2], p2[3]),
                    bfpack(q2[0], q2[1]), bfpack(q2[2], q2[3])};
        a0 = __builtin_bit_cast(s16x8, t0);
        a1 = __builtin_bit_cast(s16x8, t1);
        // az: k 64..79 -> Zr[ky 0..15], k 80..95 -> Zi[ky 0..15]; slice by g
        const unsigned short* zsrc = (g < 2) ? Zrb : Zib;
        az = *reinterpret_cast<const s16x8*>(
            zsrc + (((size_t)b * 64 + o) * 256 + h) * 16 + (g & 1) * 8);
    }
    s16x8 btr[8];
#pragma unroll
    for (int f = 0; f < 8; ++f) {
        int w = wbase + f * 16 + m;
        btr[f] = *reinterpret_cast<const s16x8*>(ttab + w * 32 + 8 * g);
    }
    f32x4 bv = *reinterpret_cast<const f32x4*>(bias + wave * 16 + 4 * g);

#pragma unroll
    for (int it = 0; it < 4; ++it) {
        int ip = it * 8 + ipg;
        const float* pa = reinterpret_cast<const float*>(&va[it]);
        const float* pb = reinterpret_cast<const float*>(&vb[it]);
#pragma unroll
        for (int j = 0; j < 4; ++j) {
            int wl = wl4 + j;
            int c = (wl ^ (wl >> 3)) & 7;
            unsigned pk = bfpack(pa[j], pb[j]);
            bsx[(wl << 5) + ((((ip >> 2) ^ c) << 2) | (ip & 3))] = pk;
        }
    }
    __syncthreads();

    f32x4 acc[8];
#pragma unroll
    for (int f = 0; f < 8; ++f)
#pragma unroll
        for (int r = 0; r < 4; ++r) acc[f][r] = 0.f;

#pragma unroll
    for (int f = 0; f < 8; ++f) {
        int wl = f * 16 + m;
        int c = (wl ^ (wl >> 3)) & 7;
        const char* rb = reinterpret_cast<const char*>(bsx) + (wl << 7);
        s16x8 bx0 = *reinterpret_cast<const s16x8*>(rb + ((g ^ c) << 4));
        s16x8 bx1 = *reinterpret_cast<const s16x8*>(rb + (((4 + g) ^ c) << 4));
        acc[f] = __builtin_amdgcn_mfma_f32_16x16x32_bf16(a0, bx0, acc[f], 0, 0, 0);
        acc[f] = __builtin_amdgcn_mfma_f32_16x16x32_bf16(a1, bx1, acc[f], 0, 0, 0);
        acc[f] = __builtin_amdgcn_mfma_f32_16x16x32_bf16(az, btr[f], acc[f], 0, 0, 0);
    }

    float* ob = out + ((size_t)(b * 64 + wave * 16 + 4 * g)) * 65536 + (size_t)h * 256 + wbase;
#pragma unroll
    for (int f = 0; f < 8; ++f) {
#pragma unroll
        for (int r = 0; r < 4; ++r)
            ob[(size_t)r * 65536 + f * 16 + m] = acc[f][r] + bv[r];
    }
}

extern "C" void kernel_launch(void* const* d_in, const int* in_sizes, int n_in,
                              void* d_out, int out_size, void* d_ws, size_t ws_size,
                              hipStream_t stream) {
    const float* x   = (const float*)d_in[0];
    const float* w1r = (const float*)d_in[1];
    const float* w1i = (const float*)d_in[2];
    const float* w2r = (const float*)d_in[3];
    const float* w2i = (const float*)d_in[4];
    const float* cw  = (const float*)d_in[5];
    const float* cb  = (const float*)d_in[6];
    float* out = (float*)d_out;
    float* ws  = (float*)d_ws;
    unsigned short* tA   = (unsigned short*)(ws + O_TA);
    unsigned short* tB   = (unsigned short*)(ws + O_TB);
    unsigned short* ttab = (unsigned short*)(ws + O_TT);
    unsigned short* tD   = (unsigned short*)(ws + O_TD);
    unsigned short* Zrb  = (unsigned short*)(ws + O_ZRB);
    unsigned short* Zib  = (unsigned short*)(ws + O_ZIB);

    ktabs<<<320, 256, 0, stream>>>(tA, tB, tD, ttab);
    kw_prep<<<256, 256, 0, stream>>>(w1r, w1i, w2r, w2i, ws + O_WTR, ws + O_WTI);
    kab_fwd<<<1024, 256, 0, stream>>>(x, tA, tB, ws + O_XRA, ws + O_XIA,
                                      ws + O_XRB, ws + O_XIB);
    kc_mix<<<1024, 256, 0, stream>>>(ws + O_XRA, ws + O_XIA, ws + O_XRB, ws + O_XIB,
                                     ws + O_WTR, ws + O_WTI,
                                     ws + O_YRA, ws + O_YIA, ws + O_YRB, ws + O_YIB);
    kd_mfma<<<1024, 256, 0, stream>>>(ws + O_YRA, ws + O_YIA, ws + O_YRB, ws + O_YIB,
                                      tD, Zrb, Zib);
    ke_mfma<<<4096, 256, 0, stream>>>(x, Zrb, Zib, cw, cb, ttab, out);
}

// Round 13
// 122.892 us; speedup vs baseline: 1.0472x; 1.0472x over previous
//
#include <hip/hip_runtime.h>
#include <math.h>

// FourierLayer: B=8, C=64, H=256, W=256, M1=M2=16.
// Pipeline:
//   AB (fused MFMA, h-split, LDS-dbuf): per (bc, h-half): phase1 U[32][128h] = TA . x^T ;
//       phase2 X_part[64][16ky] = TB[.,h-slice] . U2 ; partials summed in C.
//   ktabs: trig tables + Wt[kxi][ky][i][o] transpose (fused)
//   C: Y2[b][o][ky][kxi] (i-split partials A/B) = sum_i (XA+XB) * Wt  (complex, f32)
//   D (MFMA): Z[b][o][h][ky] bf16 = sum_kxi sc(ky)*(YrA+YrB, YiA+YiB).(trig), h-quartered
//   E (MFMA): out[64o][128w-half] = [cw | Zr | Zi] (64x96 bf16) @ [x ; cos ; -sin] + bias
//       (non-temporal out stores)

#define TWOPI_256 0.024543692606170259f   // 2*pi/256
#define INV256    0.00390625f

// ---------------- workspace layout (floats) ----------------
#define NX   262144             // X/Y size: 8*64*512
#define NWT  2097152            // 32*16*64*64
#define NZH  1048576            // bf16 Z plane: 2097152 ushort = NZH float slots
#define O_TA   0                // 8192 ushort  (32x256 bf16)
#define O_TB   4096             // 32768 ushort (64x512 bf16)
#define O_XRA  20480
#define O_XIA  (O_XRA + NX)
#define O_XRB  (O_XIA + NX)
#define O_XIB  (O_XRB + NX)
#define O_WTR  (O_XIB + NX)
#define O_WTI  (O_WTR + NWT)
#define O_YRA  (O_WTI + NWT)
#define O_YIA  (O_YRA + NX)
#define O_YRB  (O_YIA + NX)
#define O_YIB  (O_YRB + NX)
#define O_ZRB  (O_YIB + NX)     // ushort[2097152]: Zr bf16 [b][o][h][16ky]
#define O_ZIB  (O_ZRB + NZH)    // ushort[2097152]: Zi bf16
#define O_TT   (O_ZIB + NZH)    // E trig table ttab2: 8192 ushort
#define O_TD   (O_TT + 4096)    // D trig table: 32768 ushort ([2 ri][256 h][64 k])
// end = O_TD + 16384 ~= 8.43M floats ~= 33.7 MiB

using s16x8 = __attribute__((ext_vector_type(8))) short;   // 8 bf16 (4 VGPRs)
using f32x4 = __attribute__((ext_vector_type(4))) float;   // MFMA acc
using u32x4 = __attribute__((ext_vector_type(4))) unsigned;

__device__ __forceinline__ unsigned short f2bf(float f) {  // RNE f32->bf16 (table gen only)
    union { float f; unsigned u; } a; a.f = f;
    unsigned r = (a.u + 0x7fffu + ((a.u >> 16) & 1u)) >> 16;
    return (unsigned short)r;
}

// pure-C packed convert (round-half-up): lo16 = bf16(a), hi16 = bf16(b)
__device__ __forceinline__ unsigned bfpack(float a, float b) {
    union { float f; unsigned u; } x, y; x.f = a; y.f = b;
    return ((x.u + 0x8000u) >> 16) | ((y.u + 0x8000u) & 0xffff0000u);
}

// ---------------- ktabs: trig tables (blocks 0..319) + W transpose (320..575) ----
__global__ __launch_bounds__(256) void ktabs(unsigned short* __restrict__ tA,
                                             unsigned short* __restrict__ tB,
                                             unsigned short* __restrict__ tD,
                                             unsigned short* __restrict__ tT,
                                             const float* __restrict__ w1r,
                                             const float* __restrict__ w1i,
                                             const float* __restrict__ w2r,
                                             const float* __restrict__ w2i,
                                             float* __restrict__ Wtr,
                                             float* __restrict__ Wti) {
    if (blockIdx.x < 320) {
        int idx = blockIdx.x * 256 + threadIdx.x;     // 81920 total
        if (idx < 8192) {
            // TA[col][w]: col<16 -> cos(2pi col w/256)/256 ; col>=16 -> -sin(...)/256
            int col = idx >> 8, w = idx & 255;
            int ky = col & 15;
            int mm = (ky * w) & 255;
            float s, c; sincosf((float)mm * TWOPI_256, &s, &c);
            tA[idx] = f2bf(col < 16 ? c * INV256 : -s * INV256);
        } else if (idx < 40960) {
            // TB[kx2][2h+p]: kx2<32 (Re): p0=cos, p1=sin ; kx2>=32 (Im): p0=-sin, p1=cos
            int j = idx - 8192;
            int kx2 = j >> 9, k = j & 511, h = k >> 1, p = k & 1;
            int kxi = kx2 & 31;
            int kx = (kxi < 16) ? kxi : (224 + kxi);
            int mm = (kx * h) & 255;
            float s, c; sincosf((float)mm * TWOPI_256, &s, &c);
            float v;
            if (kx2 < 32) v = p ? s : c;
            else          v = p ? c : -s;
            tB[j] = f2bf(v);
        } else if (idx < 73728) {
            // TD[ri][h][k=2kxi+p], e^{+2pi i kx h/256}:
            //   ri=0 (Zr): p0 = cos, p1 = -sin ; ri=1 (Zi): p0 = sin, p1 = cos
            int j = idx - 40960;
            int ri = j >> 14, rem = j & 16383;
            int h = rem >> 6, k = rem & 63, kxi = k >> 1, p = k & 1;
            int kx = (kxi < 16) ? kxi : (224 + kxi);
            int mm = (kx * h) & 255;
            float s, c; sincosf((float)mm * TWOPI_256, &s, &c);
            float v;
            if (ri == 0) v = p ? -s : c;
            else         v = p ? c : s;
            tD[j] = f2bf(v);
        } else {
            // TT2[w][kk] for E: kk<16 -> cos(2pi kk w/256) ; kk>=16 -> -sin(2pi (kk-16) w/256)
            int j = idx - 73728;
            int w = j >> 5, kk = j & 31, ky = kk & 15;
            int mm = (ky * w) & 255;
            float s, c; sincosf((float)mm * TWOPI_256, &s, &c);
            tT[j] = f2bf(kk < 16 ? c : -s);
        }
        return;
    }
    // ---- W transpose part: Wt[kxi][ky][i][o] = w[i][o][m][ky] ----
    __shared__ float lds[128][65];
    const int tid = threadIdx.x;
    const int bb = blockIdx.x - 320;
    const int a = bb >> 6;
    const int i = bb & 63;
    const float* src = (a == 0) ? w1r : (a == 1) ? w1i : (a == 2) ? w2r : w2i;
    float* dst = (a & 1) ? Wti : Wtr;
    const int kxoff = (a >> 1) << 4;
    const float* sp = src + (size_t)i * 16384;

    for (int p = 0; p < 2; ++p) {
        if (p) __syncthreads();
#pragma unroll
        for (int it = 0; it < 8; ++it) {
            int f4 = it * 256 + tid;
            int o = f4 >> 5, j4 = f4 & 31;
            float4 v = *reinterpret_cast<const float4*>(sp + o * 256 + p * 128 + j4 * 4);
            lds[j4 * 4 + 0][o] = v.x; lds[j4 * 4 + 1][o] = v.y;
            lds[j4 * 4 + 2][o] = v.z; lds[j4 * 4 + 3][o] = v.w;
        }
        __syncthreads();
        const int o = tid & 63, mq = tid >> 6;
#pragma unroll
        for (int r = 0; r < 32; ++r) {
            int lm = r * 4 + mq;
            int mky = p * 128 + lm;
            int mm = mky >> 4, ky = mky & 15;
            dst[((((size_t)(kxoff + mm)) * 16 + ky) * 64 + i) * 64 + o] = lds[lm][o];
        }
    }
}

// ---------------- Kernel AB (fused MFMA, h-split, LDS-dbuf): x -> X partials ----
// grid 1024 = bc(512) x h-half(2). block 256 (4 waves). Double-buffered xt:
// one __syncthreads per chunk (write buf p, sync, MFMA buf p; next write hits p^1).
__global__ __launch_bounds__(256, 3) void kab_fwd(const float* __restrict__ x,
                                                  const unsigned short* __restrict__ tA,
                                                  const unsigned short* __restrict__ tB,
                                                  float* __restrict__ XrA,
                                                  float* __restrict__ XiA,
                                                  float* __restrict__ XrB,
                                                  float* __restrict__ XiB) {
    __shared__ __align__(16) unsigned short xt[2][8192]; // 2x16 KB [128h][64w] bf16 swz
    __shared__ __align__(16) unsigned int   ub[2048];    // 8 KB U2 [16ky][256k] swz
    const int tid  = threadIdx.x;
    const int bc   = blockIdx.x >> 1;
    const int hhf  = blockIdx.x & 1;
    const int hbase = hhf << 7;
    const int m    = tid & 15;
    const int g    = (tid >> 4) & 3;
    const int wave = tid >> 6;

    const float* xp = x + (size_t)bc * 65536 + (size_t)hbase * 256;
    const int hh = tid >> 4;        // 0..15: h offset within 16-row group
    const int w4 = tid & 15;        // float4 index along w

    f32x4 acc[2][2];
#pragma unroll
    for (int a = 0; a < 2; ++a)
#pragma unroll
        for (int fn = 0; fn < 2; ++fn)
#pragma unroll
            for (int r = 0; r < 4; ++r) acc[a][fn][r] = 0.f;

    float4 stg[2][8];
#pragma unroll
    for (int it = 0; it < 8; ++it)
        stg[0][it] = *reinterpret_cast<const float4*>(xp + (it * 16 + hh) * 256 + w4 * 4);

#pragma unroll
    for (int ch = 0; ch < 4; ++ch) {
        const int cur = ch & 1;
        if (ch < 3) {
#pragma unroll
            for (int it = 0; it < 8; ++it)
                stg[cur ^ 1][it] = *reinterpret_cast<const float4*>(
                    xp + (it * 16 + hh) * 256 + (ch + 1) * 64 + w4 * 4);
        }
#pragma unroll
        for (int it = 0; it < 8; ++it) {
            int h = it * 16 + hh;                    // local h 0..127
            float4 v = stg[cur][it];
            unsigned lo = bfpack(v.x, v.y);
            unsigned hi = bfpack(v.z, v.w);
            int wl  = w4 * 4;
            int blk = (wl >> 3) ^ (h & 7);
            char* p = reinterpret_cast<char*>(xt[cur]) + (h << 7) + (blk << 4) + ((wl & 7) << 1);
            *reinterpret_cast<uint2*>(p) = make_uint2(lo, hi);
        }
        __syncthreads();
#pragma unroll
        for (int ks = 0; ks < 2; ++ks) {
            s16x8 a0 = *reinterpret_cast<const s16x8*>(tA + m * 256        + ch * 64 + ks * 32 + 8 * g);
            s16x8 a1 = *reinterpret_cast<const s16x8*>(tA + (16 + m) * 256 + ch * 64 + ks * 32 + 8 * g);
#pragma unroll
            for (int fn = 0; fn < 2; ++fn) {
                int h   = wave * 32 + fn * 16 + m;   // local h
                int blk = (4 * ks + g) ^ (h & 7);
                s16x8 bf = *reinterpret_cast<const s16x8*>(
                    reinterpret_cast<const char*>(xt[cur]) + (h << 7) + (blk << 4));
                acc[0][fn] = __builtin_amdgcn_mfma_f32_16x16x32_bf16(a0, bf, acc[0][fn], 0, 0, 0);
                acc[1][fn] = __builtin_amdgcn_mfma_f32_16x16x32_bf16(a1, bf, acc[1][fn], 0, 0, 0);
            }
        }
        // no second barrier: next write targets xt[cur^1]; the barrier at the
        // top of chunk ch+1 orders MFMA(ch) before any write to xt[cur] at ch+2.
    }
    __syncthreads();

    // ---- redistribute U -> ub: word h(local) of row ky holds (Ur,Ui) bf16 pair ----
#pragma unroll
    for (int fn = 0; fn < 2; ++fn) {
        int h = wave * 32 + fn * 16 + m;
#pragma unroll
        for (int r = 0; r < 4; ++r) {
            int ky = 4 * g + r;
            unsigned pk = bfpack(acc[0][fn][r], acc[1][fn][r]);
            int blk = (h >> 2) ^ (ky & 7);
            ub[ky * 128 + blk * 4 + (h & 3)] = pk;
        }
    }
    __syncthreads();

    // ---- phase-2 MFMA: X_part[64][16] = TB[64][k-slice] . U2[256][16] ----
    f32x4 acc2;
#pragma unroll
    for (int r = 0; r < 4; ++r) acc2[r] = 0.f;
#pragma unroll
    for (int ks = 0; ks < 8; ++ks) {
        s16x8 a2 = *reinterpret_cast<const s16x8*>(tB + (wave * 16 + m) * 512 + hbase * 2 + ks * 32 + 8 * g);
        int blk = (4 * ks + g) ^ (m & 7);
        s16x8 b2 = *reinterpret_cast<const s16x8*>(
            reinterpret_cast<const char*>(ub) + m * 512 + (blk << 4));
        acc2 = __builtin_amdgcn_mfma_f32_16x16x32_bf16(a2, b2, acc2, 0, 0, 0);
    }
    float* Xr = hhf ? XrB : XrA;
    float* Xi = hhf ? XiB : XiA;
#pragma unroll
    for (int r = 0; r < 4; ++r) {
        int kx2 = wave * 16 + 4 * g + r;
        if (kx2 < 32) Xr[(size_t)bc * 512 + kx2 * 16 + m]        = acc2[r];
        else          Xi[(size_t)bc * 512 + (kx2 - 32) * 16 + m] = acc2[r];
    }
}

// ---------------- Kernel C: channel mixing (i-split) -> Y partial A/B --------
// grid 1024 = mode(512) x ih(2). Each block sums 32 i's; X = XA + XB partials.
__global__ __launch_bounds__(256) void kc_mix(const float* __restrict__ XrA,
                                              const float* __restrict__ XiA,
                                              const float* __restrict__ XrB,
                                              const float* __restrict__ XiB,
                                              const float* __restrict__ Wtr,
                                              const float* __restrict__ Wti,
                                              float* __restrict__ YrA,
                                              float* __restrict__ YiA,
                                              float* __restrict__ YrB,
                                              float* __restrict__ YiB) {
    __shared__ float xsr[256], xsi[256];
    const int tid  = threadIdx.x;
    const int mode = blockIdx.x >> 1;
    const int ih   = blockIdx.x & 1;
    {
        int b = tid >> 5, il = tid & 31;
        size_t ofs = (size_t)(b * 64 + ih * 32 + il) * 512 + mode;
        xsr[tid] = XrA[ofs] + XrB[ofs];
        xsi[tid] = XiA[ofs] + XiB[ofs];
    }
    __syncthreads();
    const int o = tid & 63, bg = tid >> 6;
    float yr0 = 0.f, yi0 = 0.f, yr1 = 0.f, yi1 = 0.f;
    const float* wrp = Wtr + (size_t)mode * 4096 + ih * 2048;
    const float* wip = Wti + (size_t)mode * 4096 + ih * 2048;
#pragma unroll 8
    for (int i = 0; i < 32; ++i) {
        float wr = wrp[i * 64 + o], wi = wip[i * 64 + o];
        float xr = xsr[bg * 32 + i],        xi = xsi[bg * 32 + i];
        yr0 += xr * wr - xi * wi;  yi0 += xr * wi + xi * wr;
        float xr2 = xsr[(bg + 4) * 32 + i], xi2 = xsi[(bg + 4) * 32 + i];
        yr1 += xr2 * wr - xi2 * wi;  yi1 += xr2 * wi + xi2 * wr;
    }
    float* Yr = ih ? YrB : YrA;
    float* Yi = ih ? YiB : YiA;
    const int kxi = mode >> 4, kym = mode & 15;
    const size_t e0 = ((size_t)bg * 64 + o) * 512 + kym * 32 + kxi;
    const size_t e1 = ((size_t)(bg + 4) * 64 + o) * 512 + kym * 32 + kxi;
    Yr[e0] = yr0;  Yi[e0] = yi0;
    Yr[e1] = yr1;  Yi[e1] = yi1;
}

// ---------------- Kernel D (MFMA): Y(A+B) -> Z bf16 [b][o][h][ky] ----------
// grid 1024 = b(8) x og(16) x ri(2) x hs(4). block 256 (4 waves, wave = 16-h frag).
__global__ __launch_bounds__(256) void kd_mfma(const float* __restrict__ YrA,
                                               const float* __restrict__ YiA,
                                               const float* __restrict__ YrB,
                                               const float* __restrict__ YiB,
                                               const unsigned short* __restrict__ tD,
                                               unsigned short* __restrict__ Zrb,
                                               unsigned short* __restrict__ Zib) {
    __shared__ __align__(16) unsigned short at[4096];   // 8 KB: A[64 rows][64 k] swz
    __shared__ __align__(16) float zt[64][68];          // 17.4 KB: [h_local][m] + pad
    const int tid = threadIdx.x;
    const int bid = blockIdx.x;
    const int b  = bid >> 7;
    const int og = (bid >> 3) & 15;
    const int ri = (bid >> 2) & 1;
    const int hs = bid & 3;

    // ---- stage A: row = ol*16+ky, word j=kxi holds (Yr*sc, Yi*sc) bf16 ----
    {
        const int row = tid >> 2, q = tid & 3;
        const int ol = row >> 4, ky = row & 15;
        const float sc = (ky == 0) ? INV256 : 2.f * INV256;
        const size_t yb = ((size_t)(b * 64 + og * 4 + ol)) * 512 + ky * 32 + q * 8;
        f32x4 r0 = *reinterpret_cast<const f32x4*>(YrA + yb)     + *reinterpret_cast<const f32x4*>(YrB + yb);
        f32x4 r1 = *reinterpret_cast<const f32x4*>(YrA + yb + 4) + *reinterpret_cast<const f32x4*>(YrB + yb + 4);
        f32x4 i0 = *reinterpret_cast<const f32x4*>(YiA + yb)     + *reinterpret_cast<const f32x4*>(YiB + yb);
        f32x4 i1 = *reinterpret_cast<const f32x4*>(YiA + yb + 4) + *reinterpret_cast<const f32x4*>(YiB + yb + 4);
        unsigned wbuf[8];
#pragma unroll
        for (int t = 0; t < 4; ++t) {
            wbuf[t]     = bfpack(r0[t] * sc, i0[t] * sc);
            wbuf[4 + t] = bfpack(r1[t] * sc, i1[t] * sc);
        }
        char* base = reinterpret_cast<char*>(at) + row * 128;
        *reinterpret_cast<uint4*>(base + (((2 * q)     ^ (row & 7)) << 4)) = *reinterpret_cast<uint4*>(&wbuf[0]);
        *reinterpret_cast<uint4*>(base + (((2 * q + 1) ^ (row & 7)) << 4)) = *reinterpret_cast<uint4*>(&wbuf[4]);
    }
    __syncthreads();

    const int m = tid & 15, g = (tid >> 4) & 3, wid = tid >> 6;
    const unsigned short* td = tD + ri * 16384;
    const int hg = hs * 64 + wid * 16 + m;

    f32x4 acc[4];
#pragma unroll
    for (int mf = 0; mf < 4; ++mf)
#pragma unroll
        for (int r = 0; r < 4; ++r) acc[mf][r] = 0.f;

#pragma unroll
    for (int ks = 0; ks < 2; ++ks) {
        s16x8 bf = *reinterpret_cast<const s16x8*>(td + hg * 64 + ks * 32 + 8 * g);
#pragma unroll
        for (int mf = 0; mf < 4; ++mf) {
            s16x8 af = *reinterpret_cast<const s16x8*>(
                reinterpret_cast<const char*>(at) + (mf * 16 + m) * 128
                + (((4 * ks + g) ^ (m & 7)) << 4));
            acc[mf] = __builtin_amdgcn_mfma_f32_16x16x32_bf16(af, bf, acc[mf], 0, 0, 0);
        }
    }

#pragma unroll
    for (int mf = 0; mf < 4; ++mf)
#pragma unroll
        for (int r = 0; r < 4; ++r)
            zt[wid * 16 + m][mf * 16 + 4 * g + r] = acc[mf][r];
    __syncthreads();

    // ---- coalesced bf16 store: lane packs 4 ky -> uint2 (8B); 512B per instr ----
    unsigned short* Zd = ri ? Zib : Zrb;
    const int ol = tid >> 6, hloc = (tid >> 2) & 15, kg = tid & 3;
#pragma unroll
    for (int hq = 0; hq < 4; ++hq) {
        f32x4 v = *reinterpret_cast<const f32x4*>(&zt[hq * 16 + hloc][ol * 16 + 4 * kg]);
        unsigned lo = bfpack(v[0], v[1]);
        unsigned hi = bfpack(v[2], v[3]);
        size_t off = (((size_t)(b * 64 + og * 4 + ol)) * 256 + hs * 64 + hq * 16 + hloc) * 16 + 4 * kg;
        *reinterpret_cast<uint2*>(Zd + off) = make_uint2(lo, hi);
    }
}

// ---------------- Kernel E (MFMA): out = [cw|Zr|Zi] @ [x;cos;-sin] + bias ----
// grid 4096 = (b, h, w-half). block 256 (4 waves; wave = 16-o group x 128 w).
__global__ __launch_bounds__(256) void ke_mfma(const float* __restrict__ x,
                                               const unsigned short* __restrict__ Zrb,
                                               const unsigned short* __restrict__ Zib,
                                               const float* __restrict__ cw,
                                               const float* __restrict__ bias,
                                               const unsigned short* __restrict__ ttab,
                                               float* __restrict__ out) {
    __shared__ unsigned int bsx[4096];   // 16 KB: [128 w][32 words], swizzled
    const int tid = threadIdx.x;
    const int b  = blockIdx.x >> 9;
    const int h  = (blockIdx.x >> 1) & 255;
    const int wh = blockIdx.x & 1;
    const int wbase = wh * 128;

    const size_t xbase = ((size_t)b * 64) * 65536 + (size_t)h * 256 + wbase;
    const int wl4 = (tid & 31) * 4;
    const int ipg = tid >> 5;
    float4 va[4], vb[4];
#pragma unroll
    for (int it = 0; it < 4; ++it) {
        int ip = it * 8 + ipg;
        va[it] = *reinterpret_cast<const float4*>(x + xbase + (size_t)(2 * ip) * 65536 + wl4);
        vb[it] = *reinterpret_cast<const float4*>(x + xbase + (size_t)(2 * ip + 1) * 65536 + wl4);
    }

    const int m = tid & 15;
    const int g = (tid >> 4) & 3;
    const int wave = tid >> 6;
    const int o = wave * 16 + m;

    s16x8 a0, a1, az;
    {
        f32x4 p  = *reinterpret_cast<const f32x4*>(cw + o * 64 + 8 * g);
        f32x4 q  = *reinterpret_cast<const f32x4*>(cw + o * 64 + 8 * g + 4);
        f32x4 p2 = *reinterpret_cast<const f32x4*>(cw + o * 64 + 32 + 8 * g);
        f32x4 q2 = *reinterpret_cast<const f32x4*>(cw + o * 64 + 32 + 8 * g + 4);
        u32x4 t0 = {bfpack(p[0], p[1]),  bfpack(p[2], p[3]),
                    bfpack(q[0], q[1]),  bfpack(q[2], q[3])};
        u32x4 t1 = {bfpack(p2[0], p2[1]), bfpack(p2[2], p2[3]),
                    bfpack(q2[0], q2[1]), bfpack(q2[2], q2[3])};
        a0 = __builtin_bit_cast(s16x8, t0);
        a1 = __builtin_bit_cast(s16x8, t1);
        // az: k 64..79 -> Zr[ky 0..15], k 80..95 -> Zi[ky 0..15]; slice by g
        const unsigned short* zsrc = (g < 2) ? Zrb : Zib;
        az = *reinterpret_cast<const s16x8*>(
            zsrc + (((size_t)b * 64 + o) * 256 + h) * 16 + (g & 1) * 8);
    }
    s16x8 btr[8];
#pragma unroll
    for (int f = 0; f < 8; ++f) {
        int w = wbase + f * 16 + m;
        btr[f] = *reinterpret_cast<const s16x8*>(ttab + w * 32 + 8 * g);
    }
    f32x4 bv = *reinterpret_cast<const f32x4*>(bias + wave * 16 + 4 * g);

#pragma unroll
    for (int it = 0; it < 4; ++it) {
        int ip = it * 8 + ipg;
        const float* pa = reinterpret_cast<const float*>(&va[it]);
        const float* pb = reinterpret_cast<const float*>(&vb[it]);
#pragma unroll
        for (int j = 0; j < 4; ++j) {
            int wl = wl4 + j;
            int c = (wl ^ (wl >> 3)) & 7;
            unsigned pk = bfpack(pa[j], pb[j]);
            bsx[(wl << 5) + ((((ip >> 2) ^ c) << 2) | (ip & 3))] = pk;
        }
    }
    __syncthreads();

    f32x4 acc[8];
#pragma unroll
    for (int f = 0; f < 8; ++f)
#pragma unroll
        for (int r = 0; r < 4; ++r) acc[f][r] = 0.f;

#pragma unroll
    for (int f = 0; f < 8; ++f) {
        int wl = f * 16 + m;
        int c = (wl ^ (wl >> 3)) & 7;
        const char* rb = reinterpret_cast<const char*>(bsx) + (wl << 7);
        s16x8 bx0 = *reinterpret_cast<const s16x8*>(rb + ((g ^ c) << 4));
        s16x8 bx1 = *reinterpret_cast<const s16x8*>(rb + (((4 + g) ^ c) << 4));
        acc[f] = __builtin_amdgcn_mfma_f32_16x16x32_bf16(a0, bx0, acc[f], 0, 0, 0);
        acc[f] = __builtin_amdgcn_mfma_f32_16x16x32_bf16(a1, bx1, acc[f], 0, 0, 0);
        acc[f] = __builtin_amdgcn_mfma_f32_16x16x32_bf16(az, btr[f], acc[f], 0, 0, 0);
    }

    float* ob = out + ((size_t)(b * 64 + wave * 16 + 4 * g)) * 65536 + (size_t)h * 256 + wbase;
#pragma unroll
    for (int f = 0; f < 8; ++f) {
#pragma unroll
        for (int r = 0; r < 4; ++r)
            __builtin_nontemporal_store(acc[f][r] + bv[r], ob + (size_t)r * 65536 + f * 16 + m);
    }
}

extern "C" void kernel_launch(void* const* d_in, const int* in_sizes, int n_in,
                              void* d_out, int out_size, void* d_ws, size_t ws_size,
                              hipStream_t stream) {
    const float* x   = (const float*)d_in[0];
    const float* w1r = (const float*)d_in[1];
    const float* w1i = (const float*)d_in[2];
    const float* w2r = (const float*)d_in[3];
    const float* w2i = (const float*)d_in[4];
    const float* cw  = (const float*)d_in[5];
    const float* cb  = (const float*)d_in[6];
    float* out = (float*)d_out;
    float* ws  = (float*)d_ws;
    unsigned short* tA   = (unsigned short*)(ws + O_TA);
    unsigned short* tB   = (unsigned short*)(ws + O_TB);
    unsigned short* ttab = (unsigned short*)(ws + O_TT);
    unsigned short* tD   = (unsigned short*)(ws + O_TD);
    unsigned short* Zrb  = (unsigned short*)(ws + O_ZRB);
    unsigned short* Zib  = (unsigned short*)(ws + O_ZIB);

    ktabs<<<576, 256, 0, stream>>>(tA, tB, tD, ttab, w1r, w1i, w2r, w2i,
                                   ws + O_WTR, ws + O_WTI);
    kab_fwd<<<1024, 256, 0, stream>>>(x, tA, tB, ws + O_XRA, ws + O_XIA,
                                      ws + O_XRB, ws + O_XIB);
    kc_mix<<<1024, 256, 0, stream>>>(ws + O_XRA, ws + O_XIA, ws + O_XRB, ws + O_XIB,
                                     ws + O_WTR, ws + O_WTI,
                                     ws + O_YRA, ws + O_YIA, ws + O_YRB, ws + O_YIB);
    kd_mfma<<<1024, 256, 0, stream>>>(ws + O_YRA, ws + O_YIA, ws + O_YRB, ws + O_YIB,
                                      tD, Zrb, Zib);
    ke_mfma<<<4096, 256, 0, stream>>>(x, Zrb, Zib, cw, cb, ttab, out);
}

// Round 14
// 121.770 us; speedup vs baseline: 1.0569x; 1.0092x over previous
//
#include <hip/hip_runtime.h>
#include <math.h>

// FourierLayer: B=8, C=64, H=256, W=256, M1=M2=16.
// Pipeline:
//   AB (fused MFMA, h-split, LDS-dbuf): per (bc, h-half): phase1 U[32][128h] = TA . x^T ;
//       phase2 X_part[64][16ky] = TB[.,h-slice] . U2 ; partials summed in C.
//   ktabs: trig tables + Wt[kxi][ky][i][o] transpose (fused)
//   C: Y2[b][o][ky][kxi] (i-split partials A/B) = sum_i (XA+XB) * Wt  (complex, f32)
//   D (MFMA, ri-merged): Z[b][o][h][ky] bf16 = sum_kxi sc(ky)*(Yr,Yi).(trig);
//       one block computes BOTH Zr and Zi from a single shared A-staging (halved Y traffic)
//   E (MFMA): out[64o][128w-half] = [cw | Zr | Zi] (64x96 bf16) @ [x ; cos ; -sin] + bias
//       (non-temporal out stores)

#define TWOPI_256 0.024543692606170259f   // 2*pi/256
#define INV256    0.00390625f

// ---------------- workspace layout (floats) ----------------
#define NX   262144             // X/Y size: 8*64*512
#define NWT  2097152            // 32*16*64*64
#define NZH  1048576            // bf16 Z plane: 2097152 ushort = NZH float slots
#define O_TA   0                // 8192 ushort  (32x256 bf16)
#define O_TB   4096             // 32768 ushort (64x512 bf16)
#define O_XRA  20480
#define O_XIA  (O_XRA + NX)
#define O_XRB  (O_XIA + NX)
#define O_XIB  (O_XRB + NX)
#define O_WTR  (O_XIB + NX)
#define O_WTI  (O_WTR + NWT)
#define O_YRA  (O_WTI + NWT)
#define O_YIA  (O_YRA + NX)
#define O_YRB  (O_YIA + NX)
#define O_YIB  (O_YRB + NX)
#define O_ZRB  (O_YIB + NX)     // ushort[2097152]: Zr bf16 [b][o][h][16ky]
#define O_ZIB  (O_ZRB + NZH)    // ushort[2097152]: Zi bf16
#define O_TT   (O_ZIB + NZH)    // E trig table ttab2: 8192 ushort
#define O_TD   (O_TT + 4096)    // D trig table: 32768 ushort ([2 ri][256 h][64 k])
// end = O_TD + 16384 ~= 8.43M floats ~= 33.7 MiB

using s16x8 = __attribute__((ext_vector_type(8))) short;   // 8 bf16 (4 VGPRs)
using f32x4 = __attribute__((ext_vector_type(4))) float;   // MFMA acc
using u32x4 = __attribute__((ext_vector_type(4))) unsigned;

__device__ __forceinline__ unsigned short f2bf(float f) {  // RNE f32->bf16 (table gen only)
    union { float f; unsigned u; } a; a.f = f;
    unsigned r = (a.u + 0x7fffu + ((a.u >> 16) & 1u)) >> 16;
    return (unsigned short)r;
}

// pure-C packed convert (round-half-up): lo16 = bf16(a), hi16 = bf16(b)
__device__ __forceinline__ unsigned bfpack(float a, float b) {
    union { float f; unsigned u; } x, y; x.f = a; y.f = b;
    return ((x.u + 0x8000u) >> 16) | ((y.u + 0x8000u) & 0xffff0000u);
}

// ---------------- ktabs: trig tables (blocks 0..319) + W transpose (320..575) ----
__global__ __launch_bounds__(256) void ktabs(unsigned short* __restrict__ tA,
                                             unsigned short* __restrict__ tB,
                                             unsigned short* __restrict__ tD,
                                             unsigned short* __restrict__ tT,
                                             const float* __restrict__ w1r,
                                             const float* __restrict__ w1i,
                                             const float* __restrict__ w2r,
                                             const float* __restrict__ w2i,
                                             float* __restrict__ Wtr,
                                             float* __restrict__ Wti) {
    if (blockIdx.x < 320) {
        int idx = blockIdx.x * 256 + threadIdx.x;     // 81920 total
        if (idx < 8192) {
            // TA[col][w]: col<16 -> cos(2pi col w/256)/256 ; col>=16 -> -sin(...)/256
            int col = idx >> 8, w = idx & 255;
            int ky = col & 15;
            int mm = (ky * w) & 255;
            float s, c; sincosf((float)mm * TWOPI_256, &s, &c);
            tA[idx] = f2bf(col < 16 ? c * INV256 : -s * INV256);
        } else if (idx < 40960) {
            // TB[kx2][2h+p]: kx2<32 (Re): p0=cos, p1=sin ; kx2>=32 (Im): p0=-sin, p1=cos
            int j = idx - 8192;
            int kx2 = j >> 9, k = j & 511, h = k >> 1, p = k & 1;
            int kxi = kx2 & 31;
            int kx = (kxi < 16) ? kxi : (224 + kxi);
            int mm = (kx * h) & 255;
            float s, c; sincosf((float)mm * TWOPI_256, &s, &c);
            float v;
            if (kx2 < 32) v = p ? s : c;
            else          v = p ? c : -s;
            tB[j] = f2bf(v);
        } else if (idx < 73728) {
            // TD[ri][h][k=2kxi+p], e^{+2pi i kx h/256}:
            //   ri=0 (Zr): p0 = cos, p1 = -sin ; ri=1 (Zi): p0 = sin, p1 = cos
            int j = idx - 40960;
            int ri = j >> 14, rem = j & 16383;
            int h = rem >> 6, k = rem & 63, kxi = k >> 1, p = k & 1;
            int kx = (kxi < 16) ? kxi : (224 + kxi);
            int mm = (kx * h) & 255;
            float s, c; sincosf((float)mm * TWOPI_256, &s, &c);
            float v;
            if (ri == 0) v = p ? -s : c;
            else         v = p ? c : s;
            tD[j] = f2bf(v);
        } else {
            // TT2[w][kk] for E: kk<16 -> cos(2pi kk w/256) ; kk>=16 -> -sin(2pi (kk-16) w/256)
            int j = idx - 73728;
            int w = j >> 5, kk = j & 31, ky = kk & 15;
            int mm = (ky * w) & 255;
            float s, c; sincosf((float)mm * TWOPI_256, &s, &c);
            tT[j] = f2bf(kk < 16 ? c : -s);
        }
        return;
    }
    // ---- W transpose part: Wt[kxi][ky][i][o] = w[i][o][m][ky] ----
    __shared__ float lds[128][65];
    const int tid = threadIdx.x;
    const int bb = blockIdx.x - 320;
    const int a = bb >> 6;
    const int i = bb & 63;
    const float* src = (a == 0) ? w1r : (a == 1) ? w1i : (a == 2) ? w2r : w2i;
    float* dst = (a & 1) ? Wti : Wtr;
    const int kxoff = (a >> 1) << 4;
    const float* sp = src + (size_t)i * 16384;

    for (int p = 0; p < 2; ++p) {
        if (p) __syncthreads();
#pragma unroll
        for (int it = 0; it < 8; ++it) {
            int f4 = it * 256 + tid;
            int o = f4 >> 5, j4 = f4 & 31;
            float4 v = *reinterpret_cast<const float4*>(sp + o * 256 + p * 128 + j4 * 4);
            lds[j4 * 4 + 0][o] = v.x; lds[j4 * 4 + 1][o] = v.y;
            lds[j4 * 4 + 2][o] = v.z; lds[j4 * 4 + 3][o] = v.w;
        }
        __syncthreads();
        const int o = tid & 63, mq = tid >> 6;
#pragma unroll
        for (int r = 0; r < 32; ++r) {
            int lm = r * 4 + mq;
            int mky = p * 128 + lm;
            int mm = mky >> 4, ky = mky & 15;
            dst[((((size_t)(kxoff + mm)) * 16 + ky) * 64 + i) * 64 + o] = lds[lm][o];
        }
    }
}

// ---------------- Kernel AB (fused MFMA, h-split, LDS-dbuf): x -> X partials ----
// grid 1024 = bc(512) x h-half(2). block 256 (4 waves). Double-buffered xt:
// one __syncthreads per chunk (write buf p, sync, MFMA buf p; next write hits p^1).
__global__ __launch_bounds__(256, 3) void kab_fwd(const float* __restrict__ x,
                                                  const unsigned short* __restrict__ tA,
                                                  const unsigned short* __restrict__ tB,
                                                  float* __restrict__ XrA,
                                                  float* __restrict__ XiA,
                                                  float* __restrict__ XrB,
                                                  float* __restrict__ XiB) {
    __shared__ __align__(16) unsigned short xt[2][8192]; // 2x16 KB [128h][64w] bf16 swz
    __shared__ __align__(16) unsigned int   ub[2048];    // 8 KB U2 [16ky][256k] swz
    const int tid  = threadIdx.x;
    const int bc   = blockIdx.x >> 1;
    const int hhf  = blockIdx.x & 1;
    const int hbase = hhf << 7;
    const int m    = tid & 15;
    const int g    = (tid >> 4) & 3;
    const int wave = tid >> 6;

    const float* xp = x + (size_t)bc * 65536 + (size_t)hbase * 256;
    const int hh = tid >> 4;        // 0..15: h offset within 16-row group
    const int w4 = tid & 15;        // float4 index along w

    f32x4 acc[2][2];
#pragma unroll
    for (int a = 0; a < 2; ++a)
#pragma unroll
        for (int fn = 0; fn < 2; ++fn)
#pragma unroll
            for (int r = 0; r < 4; ++r) acc[a][fn][r] = 0.f;

    float4 stg[2][8];
#pragma unroll
    for (int it = 0; it < 8; ++it)
        stg[0][it] = *reinterpret_cast<const float4*>(xp + (it * 16 + hh) * 256 + w4 * 4);

#pragma unroll
    for (int ch = 0; ch < 4; ++ch) {
        const int cur = ch & 1;
        if (ch < 3) {
#pragma unroll
            for (int it = 0; it < 8; ++it)
                stg[cur ^ 1][it] = *reinterpret_cast<const float4*>(
                    xp + (it * 16 + hh) * 256 + (ch + 1) * 64 + w4 * 4);
        }
#pragma unroll
        for (int it = 0; it < 8; ++it) {
            int h = it * 16 + hh;                    // local h 0..127
            float4 v = stg[cur][it];
            unsigned lo = bfpack(v.x, v.y);
            unsigned hi = bfpack(v.z, v.w);
            int wl  = w4 * 4;
            int blk = (wl >> 3) ^ (h & 7);
            char* p = reinterpret_cast<char*>(xt[cur]) + (h << 7) + (blk << 4) + ((wl & 7) << 1);
            *reinterpret_cast<uint2*>(p) = make_uint2(lo, hi);
        }
        __syncthreads();
#pragma unroll
        for (int ks = 0; ks < 2; ++ks) {
            s16x8 a0 = *reinterpret_cast<const s16x8*>(tA + m * 256        + ch * 64 + ks * 32 + 8 * g);
            s16x8 a1 = *reinterpret_cast<const s16x8*>(tA + (16 + m) * 256 + ch * 64 + ks * 32 + 8 * g);
#pragma unroll
            for (int fn = 0; fn < 2; ++fn) {
                int h   = wave * 32 + fn * 16 + m;   // local h
                int blk = (4 * ks + g) ^ (h & 7);
                s16x8 bf = *reinterpret_cast<const s16x8*>(
                    reinterpret_cast<const char*>(xt[cur]) + (h << 7) + (blk << 4));
                acc[0][fn] = __builtin_amdgcn_mfma_f32_16x16x32_bf16(a0, bf, acc[0][fn], 0, 0, 0);
                acc[1][fn] = __builtin_amdgcn_mfma_f32_16x16x32_bf16(a1, bf, acc[1][fn], 0, 0, 0);
            }
        }
        // no second barrier: next write targets xt[cur^1]; the barrier at the
        // top of chunk ch+1 orders MFMA(ch) before any write to xt[cur] at ch+2.
    }
    __syncthreads();

    // ---- redistribute U -> ub: word h(local) of row ky holds (Ur,Ui) bf16 pair ----
#pragma unroll
    for (int fn = 0; fn < 2; ++fn) {
        int h = wave * 32 + fn * 16 + m;
#pragma unroll
        for (int r = 0; r < 4; ++r) {
            int ky = 4 * g + r;
            unsigned pk = bfpack(acc[0][fn][r], acc[1][fn][r]);
            int blk = (h >> 2) ^ (ky & 7);
            ub[ky * 128 + blk * 4 + (h & 3)] = pk;
        }
    }
    __syncthreads();

    // ---- phase-2 MFMA: X_part[64][16] = TB[64][k-slice] . U2[256][16] ----
    f32x4 acc2;
#pragma unroll
    for (int r = 0; r < 4; ++r) acc2[r] = 0.f;
#pragma unroll
    for (int ks = 0; ks < 8; ++ks) {
        s16x8 a2 = *reinterpret_cast<const s16x8*>(tB + (wave * 16 + m) * 512 + hbase * 2 + ks * 32 + 8 * g);
        int blk = (4 * ks + g) ^ (m & 7);
        s16x8 b2 = *reinterpret_cast<const s16x8*>(
            reinterpret_cast<const char*>(ub) + m * 512 + (blk << 4));
        acc2 = __builtin_amdgcn_mfma_f32_16x16x32_bf16(a2, b2, acc2, 0, 0, 0);
    }
    float* Xr = hhf ? XrB : XrA;
    float* Xi = hhf ? XiB : XiA;
#pragma unroll
    for (int r = 0; r < 4; ++r) {
        int kx2 = wave * 16 + 4 * g + r;
        if (kx2 < 32) Xr[(size_t)bc * 512 + kx2 * 16 + m]        = acc2[r];
        else          Xi[(size_t)bc * 512 + (kx2 - 32) * 16 + m] = acc2[r];
    }
}

// ---------------- Kernel C: channel mixing (i-split) -> Y partial A/B --------
// grid 1024 = mode(512) x ih(2). Each block sums 32 i's; X = XA + XB partials.
__global__ __launch_bounds__(256) void kc_mix(const float* __restrict__ XrA,
                                              const float* __restrict__ XiA,
                                              const float* __restrict__ XrB,
                                              const float* __restrict__ XiB,
                                              const float* __restrict__ Wtr,
                                              const float* __restrict__ Wti,
                                              float* __restrict__ YrA,
                                              float* __restrict__ YiA,
                                              float* __restrict__ YrB,
                                              float* __restrict__ YiB) {
    __shared__ float xsr[256], xsi[256];
    const int tid  = threadIdx.x;
    const int mode = blockIdx.x >> 1;
    const int ih   = blockIdx.x & 1;
    {
        int b = tid >> 5, il = tid & 31;
        size_t ofs = (size_t)(b * 64 + ih * 32 + il) * 512 + mode;
        xsr[tid] = XrA[ofs] + XrB[ofs];
        xsi[tid] = XiA[ofs] + XiB[ofs];
    }
    __syncthreads();
    const int o = tid & 63, bg = tid >> 6;
    float yr0 = 0.f, yi0 = 0.f, yr1 = 0.f, yi1 = 0.f;
    const float* wrp = Wtr + (size_t)mode * 4096 + ih * 2048;
    const float* wip = Wti + (size_t)mode * 4096 + ih * 2048;
#pragma unroll 8
    for (int i = 0; i < 32; ++i) {
        float wr = wrp[i * 64 + o], wi = wip[i * 64 + o];
        float xr = xsr[bg * 32 + i],        xi = xsi[bg * 32 + i];
        yr0 += xr * wr - xi * wi;  yi0 += xr * wi + xi * wr;
        float xr2 = xsr[(bg + 4) * 32 + i], xi2 = xsi[(bg + 4) * 32 + i];
        yr1 += xr2 * wr - xi2 * wi;  yi1 += xr2 * wi + xi2 * wr;
    }
    float* Yr = ih ? YrB : YrA;
    float* Yi = ih ? YiB : YiA;
    const int kxi = mode >> 4, kym = mode & 15;
    const size_t e0 = ((size_t)bg * 64 + o) * 512 + kym * 32 + kxi;
    const size_t e1 = ((size_t)(bg + 4) * 64 + o) * 512 + kym * 32 + kxi;
    Yr[e0] = yr0;  Yi[e0] = yi0;
    Yr[e1] = yr1;  Yi[e1] = yi1;
}

// ---------------- Kernel D (MFMA, ri-merged): Y(A+B) -> Zr AND Zi bf16 --------
// grid 512 = b(8) x og(16) x hs(4). block 256 (4 waves, wave = 16-h frag).
// One shared A-staging (packed (Yr,Yi) pairs) feeds both ri passes; zt reused.
__global__ __launch_bounds__(256) void kd_mfma(const float* __restrict__ YrA,
                                               const float* __restrict__ YiA,
                                               const float* __restrict__ YrB,
                                               const float* __restrict__ YiB,
                                               const unsigned short* __restrict__ tD,
                                               unsigned short* __restrict__ Zrb,
                                               unsigned short* __restrict__ Zib) {
    __shared__ __align__(16) unsigned short at[4096];   // 8 KB: A[64 rows][64 k] swz
    __shared__ __align__(16) float zt[64][68];          // 17.4 KB: [h_local][m] + pad
    const int tid = threadIdx.x;
    const int bid = blockIdx.x;
    const int b  = bid >> 6;
    const int og = (bid >> 2) & 15;
    const int hs = bid & 3;

    // ---- stage A: row = ol*16+ky, word j=kxi holds (Yr*sc, Yi*sc) bf16 ----
    {
        const int row = tid >> 2, q = tid & 3;
        const int ol = row >> 4, ky = row & 15;
        const float sc = (ky == 0) ? INV256 : 2.f * INV256;
        const size_t yb = ((size_t)(b * 64 + og * 4 + ol)) * 512 + ky * 32 + q * 8;
        f32x4 r0 = *reinterpret_cast<const f32x4*>(YrA + yb)     + *reinterpret_cast<const f32x4*>(YrB + yb);
        f32x4 r1 = *reinterpret_cast<const f32x4*>(YrA + yb + 4) + *reinterpret_cast<const f32x4*>(YrB + yb + 4);
        f32x4 i0 = *reinterpret_cast<const f32x4*>(YiA + yb)     + *reinterpret_cast<const f32x4*>(YiB + yb);
        f32x4 i1 = *reinterpret_cast<const f32x4*>(YiA + yb + 4) + *reinterpret_cast<const f32x4*>(YiB + yb + 4);
        unsigned wbuf[8];
#pragma unroll
        for (int t = 0; t < 4; ++t) {
            wbuf[t]     = bfpack(r0[t] * sc, i0[t] * sc);
            wbuf[4 + t] = bfpack(r1[t] * sc, i1[t] * sc);
        }
        char* base = reinterpret_cast<char*>(at) + row * 128;
        *reinterpret_cast<uint4*>(base + (((2 * q)     ^ (row & 7)) << 4)) = *reinterpret_cast<uint4*>(&wbuf[0]);
        *reinterpret_cast<uint4*>(base + (((2 * q + 1) ^ (row & 7)) << 4)) = *reinterpret_cast<uint4*>(&wbuf[4]);
    }
    __syncthreads();

    const int m = tid & 15, g = (tid >> 4) & 3, wid = tid >> 6;
    const int hg = hs * 64 + wid * 16 + m;
    const int ol = tid >> 6, hloc = (tid >> 2) & 15, kg = tid & 3;

    // ---- hoist A-fragments once (shared across both ri passes) ----
    s16x8 af[2][4];
#pragma unroll
    for (int ks = 0; ks < 2; ++ks)
#pragma unroll
        for (int mf = 0; mf < 4; ++mf)
            af[ks][mf] = *reinterpret_cast<const s16x8*>(
                reinterpret_cast<const char*>(at) + (mf * 16 + m) * 128
                + (((4 * ks + g) ^ (m & 7)) << 4));

#pragma unroll
    for (int ri = 0; ri < 2; ++ri) {
        const unsigned short* td = tD + ri * 16384;
        f32x4 acc[4];
#pragma unroll
        for (int mf = 0; mf < 4; ++mf)
#pragma unroll
            for (int r = 0; r < 4; ++r) acc[mf][r] = 0.f;

#pragma unroll
        for (int ks = 0; ks < 2; ++ks) {
            s16x8 bf = *reinterpret_cast<const s16x8*>(td + hg * 64 + ks * 32 + 8 * g);
#pragma unroll
            for (int mf = 0; mf < 4; ++mf)
                acc[mf] = __builtin_amdgcn_mfma_f32_16x16x32_bf16(af[ks][mf], bf, acc[mf], 0, 0, 0);
        }

        if (ri) __syncthreads();   // ensure ri=0's zt reads finished before rewrite
#pragma unroll
        for (int mf = 0; mf < 4; ++mf)
#pragma unroll
            for (int r = 0; r < 4; ++r)
                zt[wid * 16 + m][mf * 16 + 4 * g + r] = acc[mf][r];
        __syncthreads();

        // ---- coalesced bf16 store: lane packs 4 ky -> uint2 (8B) ----
        unsigned short* Zd = ri ? Zib : Zrb;
#pragma unroll
        for (int hq = 0; hq < 4; ++hq) {
            f32x4 v = *reinterpret_cast<const f32x4*>(&zt[hq * 16 + hloc][ol * 16 + 4 * kg]);
            unsigned lo = bfpack(v[0], v[1]);
            unsigned hi = bfpack(v[2], v[3]);
            size_t off = (((size_t)(b * 64 + og * 4 + ol)) * 256 + hs * 64 + hq * 16 + hloc) * 16 + 4 * kg;
            *reinterpret_cast<uint2*>(Zd + off) = make_uint2(lo, hi);
        }
    }
}

// ---------------- Kernel E (MFMA): out = [cw|Zr|Zi] @ [x;cos;-sin] + bias ----
// grid 4096 = (b, h, w-half). block 256 (4 waves; wave = 16-o group x 128 w).
__global__ __launch_bounds__(256) void ke_mfma(const float* __restrict__ x,
                                               const unsigned short* __restrict__ Zrb,
                                               const unsigned short* __restrict__ Zib,
                                               const float* __restrict__ cw,
                                               const float* __restrict__ bias,
                                               const unsigned short* __restrict__ ttab,
                                               float* __restrict__ out) {
    __shared__ unsigned int bsx[4096];   // 16 KB: [128 w][32 words], swizzled
    const int tid = threadIdx.x;
    const int b  = blockIdx.x >> 9;
    const int h  = (blockIdx.x >> 1) & 255;
    const int wh = blockIdx.x & 1;
    const int wbase = wh * 128;

    const size_t xbase = ((size_t)b * 64) * 65536 + (size_t)h * 256 + wbase;
    const int wl4 = (tid & 31) * 4;
    const int ipg = tid >> 5;
    float4 va[4], vb[4];
#pragma unroll
    for (int it = 0; it < 4; ++it) {
        int ip = it * 8 + ipg;
        va[it] = *reinterpret_cast<const float4*>(x + xbase + (size_t)(2 * ip) * 65536 + wl4);
        vb[it] = *reinterpret_cast<const float4*>(x + xbase + (size_t)(2 * ip + 1) * 65536 + wl4);
    }

    const int m = tid & 15;
    const int g = (tid >> 4) & 3;
    const int wave = tid >> 6;
    const int o = wave * 16 + m;

    s16x8 a0, a1, az;
    {
        f32x4 p  = *reinterpret_cast<const f32x4*>(cw + o * 64 + 8 * g);
        f32x4 q  = *reinterpret_cast<const f32x4*>(cw + o * 64 + 8 * g + 4);
        f32x4 p2 = *reinterpret_cast<const f32x4*>(cw + o * 64 + 32 + 8 * g);
        f32x4 q2 = *reinterpret_cast<const f32x4*>(cw + o * 64 + 32 + 8 * g + 4);
        u32x4 t0 = {bfpack(p[0], p[1]),  bfpack(p[2], p[3]),
                    bfpack(q[0], q[1]),  bfpack(q[2], q[3])};
        u32x4 t1 = {bfpack(p2[0], p2[1]), bfpack(p2[2], p2[3]),
                    bfpack(q2[0], q2[1]), bfpack(q2[2], q2[3])};
        a0 = __builtin_bit_cast(s16x8, t0);
        a1 = __builtin_bit_cast(s16x8, t1);
        // az: k 64..79 -> Zr[ky 0..15], k 80..95 -> Zi[ky 0..15]; slice by g
        const unsigned short* zsrc = (g < 2) ? Zrb : Zib;
        az = *reinterpret_cast<const s16x8*>(
            zsrc + (((size_t)b * 64 + o) * 256 + h) * 16 + (g & 1) * 8);
    }
    s16x8 btr[8];
#pragma unroll
    for (int f = 0; f < 8; ++f) {
        int w = wbase + f * 16 + m;
        btr[f] = *reinterpret_cast<const s16x8*>(ttab + w * 32 + 8 * g);
    }
    f32x4 bv = *reinterpret_cast<const f32x4*>(bias + wave * 16 + 4 * g);

#pragma unroll
    for (int it = 0; it < 4; ++it) {
        int ip = it * 8 + ipg;
        const float* pa = reinterpret_cast<const float*>(&va[it]);
        const float* pb = reinterpret_cast<const float*>(&vb[it]);
#pragma unroll
        for (int j = 0; j < 4; ++j) {
            int wl = wl4 + j;
            int c = (wl ^ (wl >> 3)) & 7;
            unsigned pk = bfpack(pa[j], pb[j]);
            bsx[(wl << 5) + ((((ip >> 2) ^ c) << 2) | (ip & 3))] = pk;
        }
    }
    __syncthreads();

    f32x4 acc[8];
#pragma unroll
    for (int f = 0; f < 8; ++f)
#pragma unroll
        for (int r = 0; r < 4; ++r) acc[f][r] = 0.f;

#pragma unroll
    for (int f = 0; f < 8; ++f) {
        int wl = f * 16 + m;
        int c = (wl ^ (wl >> 3)) & 7;
        const char* rb = reinterpret_cast<const char*>(bsx) + (wl << 7);
        s16x8 bx0 = *reinterpret_cast<const s16x8*>(rb + ((g ^ c) << 4));
        s16x8 bx1 = *reinterpret_cast<const s16x8*>(rb + (((4 + g) ^ c) << 4));
        acc[f] = __builtin_amdgcn_mfma_f32_16x16x32_bf16(a0, bx0, acc[f], 0, 0, 0);
        acc[f] = __builtin_amdgcn_mfma_f32_16x16x32_bf16(a1, bx1, acc[f], 0, 0, 0);
        acc[f] = __builtin_amdgcn_mfma_f32_16x16x32_bf16(az, btr[f], acc[f], 0, 0, 0);
    }

    float* ob = out + ((size_t)(b * 64 + wave * 16 + 4 * g)) * 65536 + (size_t)h * 256 + wbase;
#pragma unroll
    for (int f = 0; f < 8; ++f) {
#pragma unroll
        for (int r = 0; r < 4; ++r)
            __builtin_nontemporal_store(acc[f][r] + bv[r], ob + (size_t)r * 65536 + f * 16 + m);
    }
}

extern "C" void kernel_launch(void* const* d_in, const int* in_sizes, int n_in,
                              void* d_out, int out_size, void* d_ws, size_t ws_size,
                              hipStream_t stream) {
    const float* x   = (const float*)d_in[0];
    const float* w1r = (const float*)d_in[1];
    const float* w1i = (const float*)d_in[2];
    const float* w2r = (const float*)d_in[3];
    const float* w2i = (const float*)d_in[4];
    const float* cw  = (const float*)d_in[5];
    const float* cb  = (const float*)d_in[6];
    float* out = (float*)d_out;
    float* ws  = (float*)d_ws;
    unsigned short* tA   = (unsigned short*)(ws + O_TA);
    unsigned short* tB   = (unsigned short*)(ws + O_TB);
    unsigned short* ttab = (unsigned short*)(ws + O_TT);
    unsigned short* tD   = (unsigned short*)(ws + O_TD);
    unsigned short* Zrb  = (unsigned short*)(ws + O_ZRB);
    unsigned short* Zib  = (unsigned short*)(ws + O_ZIB);

    ktabs<<<576, 256, 0, stream>>>(tA, tB, tD, ttab, w1r, w1i, w2r, w2i,
                                   ws + O_WTR, ws + O_WTI);
    kab_fwd<<<1024, 256, 0, stream>>>(x, tA, tB, ws + O_XRA, ws + O_XIA,
                                      ws + O_XRB, ws + O_XIB);
    kc_mix<<<1024, 256, 0, stream>>>(ws + O_XRA, ws + O_XIA, ws + O_XRB, ws + O_XIB,
                                     ws + O_WTR, ws + O_WTI,
                                     ws + O_YRA, ws + O_YIA, ws + O_YRB, ws + O_YIB);
    kd_mfma<<<512, 256, 0, stream>>>(ws + O_YRA, ws + O_YIA, ws + O_YRB, ws + O_YIB,
                                     tD, Zrb, Zib);
    ke_mfma<<<4096, 256, 0, stream>>>(x, Zrb, Zib, cw, cb, ttab, out);
}